// Round 7
// baseline (280.838 us; speedup 1.0000x reference)
//
#include <hip/hip_runtime.h>
#include <hip/hip_cooperative_groups.h>

namespace cg = cooperative_groups;

// Problem constants (from reference setup_inputs): B=16, C=64, H=W=256.
#define NB 16
#define NC 64
#define HW 65536            // 256*256
#define QHW 16384           // quarter plane (fallback stats)
#define BN_EPS 1e-5f
#define NBLK 1024           // PROVEN co-resident (R4). Do not raise.
#define NTHR 256
#define NTHREADS (NBLK * NTHR)   // 262144

typedef float f4 __attribute__((ext_vector_type(4)));

// ===========================================================================
// FUSED cooperative kernel (primary path).
// Phase 1: block bc reduces plane (b,c); loads batched 8x for MLP.
// grid.sync()
// Phase 2: redundant per-block finalize -> sc/sh in LDS.
// Phase 3: apply; 64 f4/thread in 8 batches of {8 x-loads + 8 mask-loads}
//          issued back-to-back (16 outstanding loads/thread), nt stores.
// ===========================================================================
__global__ __launch_bounds__(NTHR, 4) void mbn_fused(const float* __restrict__ x,
                                                     const float* __restrict__ mask,
                                                     const float* __restrict__ weight,
                                                     const float* __restrict__ bias,
                                                     float* __restrict__ ws,
                                                     float* __restrict__ out) {
    // ---------------- Phase 1: per-plane masked stats ----------------
    const int bc = blockIdx.x;          // 0..1023
    const int b  = bc >> 6;
    const float* xp = x + (size_t)bc * HW;
    const float* mp = mask + (size_t)b * HW;

    float s = 0.f, ss = 0.f, cn = 0.f;
    const int t0 = threadIdx.x * 4;
    for (int g = 0; g < 8; ++g) {                    // 8 groups x 8 f4 = 64 f4
        f4 xv[8], mv[8];
        #pragma unroll
        for (int u = 0; u < 8; ++u) {
            const int i = t0 + (g * 8 + u) * (NTHR * 4);
            xv[u] = *reinterpret_cast<const f4*>(xp + i);
            mv[u] = *reinterpret_cast<const f4*>(mp + i);
        }
        #pragma unroll
        for (int u = 0; u < 8; ++u) {
            float v0 = mv[u].x > 0.5f ? 1.f : 0.f;
            float v1 = mv[u].y > 0.5f ? 1.f : 0.f;
            float v2 = mv[u].z > 0.5f ? 1.f : 0.f;
            float v3 = mv[u].w > 0.5f ? 1.f : 0.f;
            s  += xv[u].x * v0 + xv[u].y * v1 + xv[u].z * v2 + xv[u].w * v3;
            ss += xv[u].x * xv[u].x * v0 + xv[u].y * xv[u].y * v1
                + xv[u].z * xv[u].z * v2 + xv[u].w * xv[u].w * v3;
            cn += v0 + v1 + v2 + v3;
        }
    }
    for (int off = 32; off > 0; off >>= 1) {
        s  += __shfl_down(s,  off);
        ss += __shfl_down(ss, off);
        cn += __shfl_down(cn, off);
    }
    __shared__ float red[3][4];
    {
        const int wave = threadIdx.x >> 6;
        const int lane = threadIdx.x & 63;
        if (lane == 0) { red[0][wave] = s; red[1][wave] = ss; red[2][wave] = cn; }
    }
    __syncthreads();
    if (threadIdx.x == 0) {
        ws[bc]        = red[0][0] + red[0][1] + red[0][2] + red[0][3];
        ws[1024 + bc] = red[1][0] + red[1][1] + red[1][2] + red[1][3];
        ws[2048 + bc] = red[2][0] + red[2][1] + red[2][2] + red[2][3];
    }

    cg::this_grid().sync();

    // ---------------- Phase 2: redundant per-block finalize ----------------
    __shared__ float sc[NC], sh[NC];
    if (threadIdx.x < NC) {
        const int c = threadIdx.x;
        float fm = 0.f, fv = 0.f;
        for (int bb = 0; bb < NB; ++bb) {
            const int i0 = bb * NC + c;
            const float S  = ws[i0];
            const float SS = ws[1024 + i0];
            const float CN = ws[2048 + i0];
            const float safe = fmaxf(CN, 1.f);
            const float mean = (CN > 0.f) ? (S / safe) : 0.f;
            const float sq   = SS - 2.f * mean * S + mean * mean * CN;
            const float var  = (CN > 1.f) ? (sq / safe) : 1.f;
            fm += mean;
            fv += var;
        }
        fm *= (1.f / NB);
        fv *= (1.f / NB);
        const float inv = 1.f / sqrtf(fv + BN_EPS);
        sc[c] = weight[c] * inv;
        sh[c] = bias[c] - fm * sc[c];
    }
    __syncthreads();

    // ---------------- Phase 3: apply, 8 batches of 8 (static idx) ----------
    const size_t base = (size_t)blockIdx.x * NTHR + threadIdx.x;
    for (int g = 0; g < 8; ++g) {
        f4 xv[8], mv[8];
        #pragma unroll
        for (int u = 0; u < 8; ++u) {
            const size_t e = (base + (size_t)(g * 8 + u) * NTHREADS) * 4;
            xv[u] = *reinterpret_cast<const f4*>(x + e);
            const size_t bb = e >> 22;
            const size_t hw = e & 65535;
            mv[u] = *reinterpret_cast<const f4*>(mask + (bb << 16) + hw);
        }
        #pragma unroll
        for (int u = 0; u < 8; ++u) {
            const size_t e = (base + (size_t)(g * 8 + u) * NTHREADS) * 4;
            const int   c  = (int)((e >> 16) & 63);
            const float scc = sc[c];
            const float shc = sh[c];
            f4 o;
            o.x = mv[u].x > 0.5f ? fmaf(xv[u].x, scc, shc) : xv[u].x;
            o.y = mv[u].y > 0.5f ? fmaf(xv[u].y, scc, shc) : xv[u].y;
            o.z = mv[u].z > 0.5f ? fmaf(xv[u].z, scc, shc) : xv[u].z;
            o.w = mv[u].w > 0.5f ? fmaf(xv[u].w, scc, shc) : xv[u].w;
            __builtin_nontemporal_store(o, reinterpret_cast<f4*>(out + e));
        }
    }
}

// ===========================================================================
// FALLBACK split kernels (R5-proven, 140 µs) — used if coop launch fails.
// ===========================================================================
__global__ __launch_bounds__(256) void mbn_stats(const float* __restrict__ x,
                                                 const float* __restrict__ mask,
                                                 float* __restrict__ ws) {
    const int blk = blockIdx.x;         // 0..4095
    const int bc  = blk >> 2;
    const int q   = blk & 3;
    const int b   = bc >> 6;
    const float* xp = x + (size_t)bc * HW + (size_t)q * QHW;
    const float* mp = mask + (size_t)b * HW + (size_t)q * QHW;

    float s = 0.f, ss = 0.f, cn = 0.f;
    #pragma unroll 4
    for (int i = threadIdx.x * 4; i < QHW; i += 256 * 4) {
        f4 xv = *reinterpret_cast<const f4*>(xp + i);
        f4 mv = *reinterpret_cast<const f4*>(mp + i);
        float v0 = mv.x > 0.5f ? 1.f : 0.f;
        float v1 = mv.y > 0.5f ? 1.f : 0.f;
        float v2 = mv.z > 0.5f ? 1.f : 0.f;
        float v3 = mv.w > 0.5f ? 1.f : 0.f;
        s  += xv.x * v0 + xv.y * v1 + xv.z * v2 + xv.w * v3;
        ss += xv.x * xv.x * v0 + xv.y * xv.y * v1
            + xv.z * xv.z * v2 + xv.w * xv.w * v3;
        cn += v0 + v1 + v2 + v3;
    }
    for (int off = 32; off > 0; off >>= 1) {
        s  += __shfl_down(s,  off);
        ss += __shfl_down(ss, off);
        cn += __shfl_down(cn, off);
    }
    __shared__ float red[3][4];
    const int wave = threadIdx.x >> 6;
    const int lane = threadIdx.x & 63;
    if (lane == 0) { red[0][wave] = s; red[1][wave] = ss; red[2][wave] = cn; }
    __syncthreads();
    if (threadIdx.x == 0) {
        ws[3072 + blk]         = red[0][0] + red[0][1] + red[0][2] + red[0][3];
        ws[3072 + 4096 + blk]  = red[1][0] + red[1][1] + red[1][2] + red[1][3];
        ws[3072 + 8192 + blk]  = red[2][0] + red[2][1] + red[2][2] + red[2][3];
    }
}

__global__ __launch_bounds__(64) void mbn_finalize(const float* __restrict__ wsq,
                                                   const float* __restrict__ weight,
                                                   const float* __restrict__ bias,
                                                   float* __restrict__ sc_sh) {
    const int c = threadIdx.x;
    float fm = 0.f, fv = 0.f;
    for (int b = 0; b < NB; ++b) {
        const int i0 = (b * NC + c) * 4;
        const float s  = wsq[i0] + wsq[i0+1] + wsq[i0+2] + wsq[i0+3];
        const float ss = wsq[4096+i0] + wsq[4096+i0+1] + wsq[4096+i0+2] + wsq[4096+i0+3];
        const float cn = wsq[8192+i0] + wsq[8192+i0+1] + wsq[8192+i0+2] + wsq[8192+i0+3];
        const float safe = fmaxf(cn, 1.f);
        const float mean = (cn > 0.f) ? (s / safe) : 0.f;
        const float sq   = ss - 2.f * mean * s + mean * mean * cn;
        const float var  = (cn > 1.f) ? (sq / safe) : 1.f;
        fm += mean;
        fv += var;
    }
    fm *= (1.f / NB);
    fv *= (1.f / NB);
    const float inv   = 1.f / sqrtf(fv + BN_EPS);
    const float scale = weight[c] * inv;
    sc_sh[c]      = scale;
    sc_sh[64 + c] = bias[c] - fm * scale;
}

__global__ __launch_bounds__(256) void mbn_apply(const float* __restrict__ x,
                                                 const float* __restrict__ mask,
                                                 const float* __restrict__ sc_sh,
                                                 float* __restrict__ out) {
    const size_t total4 = (size_t)NB * NC * HW / 4;
    const size_t stride = (size_t)gridDim.x * blockDim.x;
    for (size_t i = (size_t)blockIdx.x * blockDim.x + threadIdx.x;
         i < total4; i += stride) {
        const size_t e  = i * 4;
        const int    c  = (int)((e >> 16) & 63);
        const size_t bb = e >> 22;
        const size_t hw = e & 65535;
        f4 xv = *reinterpret_cast<const f4*>(x + e);
        f4 mv = *reinterpret_cast<const f4*>(mask + (bb << 16) + hw);
        const float sc = sc_sh[c];
        const float sh = sc_sh[64 + c];
        f4 o;
        o.x = mv.x > 0.5f ? fmaf(xv.x, sc, sh) : xv.x;
        o.y = mv.y > 0.5f ? fmaf(xv.y, sc, sh) : xv.y;
        o.z = mv.z > 0.5f ? fmaf(xv.z, sc, sh) : xv.z;
        o.w = mv.w > 0.5f ? fmaf(xv.w, sc, sh) : xv.w;
        __builtin_nontemporal_store(o, reinterpret_cast<f4*>(out + e));
    }
}

extern "C" void kernel_launch(void* const* d_in, const int* in_sizes, int n_in,
                              void* d_out, int out_size, void* d_ws, size_t ws_size,
                              hipStream_t stream) {
    const float* x      = (const float*)d_in[0];
    const float* mask   = (const float*)d_in[1];
    const float* weight = (const float*)d_in[2];
    const float* bias   = (const float*)d_in[3];
    float* out = (float*)d_out;
    float* ws  = (float*)d_ws;
    // ws layout: fused s[1024] ss[1024] cn[1024] | split q-stats[3*4096] | sc_sh[128]
    float* wsq   = ws + 3072;
    float* sc_sh = ws + 3072 + 12288;

    void* args[] = {(void*)&x, (void*)&mask, (void*)&weight, (void*)&bias,
                    (void*)&ws, (void*)&out};
    hipError_t err = hipLaunchCooperativeKernel((const void*)mbn_fused,
                                                dim3(NBLK), dim3(NTHR),
                                                args, 0, stream);
    if (err != hipSuccess) {
        // Deterministic fallback: proven split path.
        mbn_stats<<<4096, 256, 0, stream>>>(x, mask, ws);
        mbn_finalize<<<1, 64, 0, stream>>>(wsq, weight, bias, sc_sh);
        mbn_apply<<<8192, 256, 0, stream>>>(x, mask, sc_sh, out);
    }
}

// Round 8
// 139.192 us; speedup vs baseline: 2.0176x; 2.0176x over previous
//
#include <hip/hip_runtime.h>

// Problem constants (from reference setup_inputs): B=16, C=64, H=W=256.
#define NB 16
#define NC 64
#define HW 65536            // 256*256
#define QHW 16384           // HW/4
#define BN_EPS 1e-5f

typedef float f4 __attribute__((ext_vector_type(4)));

// ---------------------------------------------------------------------------
// Kernel 1: per-(b,c,quarter) masked reduction. 4096 blocks x 256 threads.
// Each block reduces a quarter (b,c) plane: 16 float4 loads of x + mask.
// ws layout: psum[4096] | psumsq[4096] | pcnt[4096] | scale[64] | shift[64]
// ---------------------------------------------------------------------------
__global__ __launch_bounds__(256) void mbn_stats(const float* __restrict__ x,
                                                 const float* __restrict__ mask,
                                                 float* __restrict__ ws) {
    const int blk = blockIdx.x;         // 0..4095
    const int bc  = blk >> 2;
    const int q   = blk & 3;
    const int b   = bc >> 6;
    const float* xp = x + (size_t)bc * HW + (size_t)q * QHW;
    const float* mp = mask + (size_t)b * HW + (size_t)q * QHW;

    float s = 0.f, ss = 0.f, cn = 0.f;
    #pragma unroll 4
    for (int i = threadIdx.x * 4; i < QHW; i += 256 * 4) {
        f4 xv = *reinterpret_cast<const f4*>(xp + i);
        f4 mv = *reinterpret_cast<const f4*>(mp + i);
        float v0 = mv.x > 0.5f ? 1.f : 0.f;
        float v1 = mv.y > 0.5f ? 1.f : 0.f;
        float v2 = mv.z > 0.5f ? 1.f : 0.f;
        float v3 = mv.w > 0.5f ? 1.f : 0.f;
        s  += xv.x * v0 + xv.y * v1 + xv.z * v2 + xv.w * v3;
        ss += xv.x * xv.x * v0 + xv.y * xv.y * v1
            + xv.z * xv.z * v2 + xv.w * xv.w * v3;
        cn += v0 + v1 + v2 + v3;
    }

    for (int off = 32; off > 0; off >>= 1) {
        s  += __shfl_down(s,  off);
        ss += __shfl_down(ss, off);
        cn += __shfl_down(cn, off);
    }
    __shared__ float red[3][4];
    const int wave = threadIdx.x >> 6;
    const int lane = threadIdx.x & 63;
    if (lane == 0) { red[0][wave] = s; red[1][wave] = ss; red[2][wave] = cn; }
    __syncthreads();
    if (threadIdx.x == 0) {
        ws[blk]        = red[0][0] + red[0][1] + red[0][2] + red[0][3];
        ws[4096 + blk] = red[1][0] + red[1][1] + red[1][2] + red[1][3];
        ws[8192 + blk] = red[2][0] + red[2][1] + red[2][2] + red[2][3];
    }
}

// ---------------------------------------------------------------------------
// Kernel 2: fold quarter-stats -> per-channel scale/shift. Reference edge
// semantics: mean=0 if cnt==0, var=1 if cnt<=1 (per (b,c) BEFORE batch-mean).
// ---------------------------------------------------------------------------
__global__ __launch_bounds__(64) void mbn_finalize(const float* __restrict__ ws_in,
                                                   const float* __restrict__ weight,
                                                   const float* __restrict__ bias,
                                                   float* __restrict__ sc_sh) {
    const int c = threadIdx.x;          // 0..63
    float fm = 0.f, fv = 0.f;
    for (int b = 0; b < NB; ++b) {
        const int i0 = (b * NC + c) * 4;
        const float s  = ws_in[i0]        + ws_in[i0 + 1]
                       + ws_in[i0 + 2]    + ws_in[i0 + 3];
        const float ss = ws_in[4096 + i0] + ws_in[4096 + i0 + 1]
                       + ws_in[4096 + i0 + 2] + ws_in[4096 + i0 + 3];
        const float cn = ws_in[8192 + i0] + ws_in[8192 + i0 + 1]
                       + ws_in[8192 + i0 + 2] + ws_in[8192 + i0 + 3];
        const float safe = fmaxf(cn, 1.f);
        const float mean = (cn > 0.f) ? (s / safe) : 0.f;
        const float sq   = ss - 2.f * mean * s + mean * mean * cn;
        const float var  = (cn > 1.f) ? (sq / safe) : 1.f;
        fm += mean;
        fv += var;
    }
    fm *= (1.f / NB);
    fv *= (1.f / NB);
    const float inv   = 1.f / sqrtf(fv + BN_EPS);
    const float scale = weight[c] * inv;
    const float shift = bias[c] - fm * scale;
    sc_sh[c]      = scale;
    sc_sh[64 + c] = shift;
}

// ---------------------------------------------------------------------------
// Kernel 3: elementwise apply: out = valid ? x*scale[c]+shift[c] : x
// 8192 blocks, float4 grid-stride (8 iters/thread), plain loads,
// nontemporal stores.
// ---------------------------------------------------------------------------
__global__ __launch_bounds__(256) void mbn_apply(const float* __restrict__ x,
                                                 const float* __restrict__ mask,
                                                 const float* __restrict__ sc_sh,
                                                 float* __restrict__ out) {
    const size_t total4 = (size_t)NB * NC * HW / 4;   // 16,777,216 float4s
    const size_t stride = (size_t)gridDim.x * blockDim.x;
    for (size_t i = (size_t)blockIdx.x * blockDim.x + threadIdx.x;
         i < total4; i += stride) {
        const size_t e  = i * 4;
        const int    c  = (int)((e >> 16) & 63);
        const size_t b  = e >> 22;
        const size_t hw = e & 65535;
        f4 xv = *reinterpret_cast<const f4*>(x + e);
        f4 mv = *reinterpret_cast<const f4*>(mask + (b << 16) + hw);
        const float sc = sc_sh[c];
        const float sh = sc_sh[64 + c];
        f4 o;
        o.x = mv.x > 0.5f ? fmaf(xv.x, sc, sh) : xv.x;
        o.y = mv.y > 0.5f ? fmaf(xv.y, sc, sh) : xv.y;
        o.z = mv.z > 0.5f ? fmaf(xv.z, sc, sh) : xv.z;
        o.w = mv.w > 0.5f ? fmaf(xv.w, sc, sh) : xv.w;
        __builtin_nontemporal_store(o, reinterpret_cast<f4*>(out + e));
    }
}

extern "C" void kernel_launch(void* const* d_in, const int* in_sizes, int n_in,
                              void* d_out, int out_size, void* d_ws, size_t ws_size,
                              hipStream_t stream) {
    const float* x      = (const float*)d_in[0];
    const float* mask   = (const float*)d_in[1];
    const float* weight = (const float*)d_in[2];
    const float* bias   = (const float*)d_in[3];
    float* out   = (float*)d_out;
    float* ws    = (float*)d_ws;      // psum[4096] psumsq[4096] pcnt[4096]
    float* sc_sh = ws + 12288;        // scale[64] shift[64]

    mbn_stats<<<4096, 256, 0, stream>>>(x, mask, ws);
    mbn_finalize<<<1, 64, 0, stream>>>(ws, weight, bias, sc_sh);
    mbn_apply<<<8192, 256, 0, stream>>>(x, mask, sc_sh, out);
}